// Round 1
// baseline (71.783 us; speedup 1.0000x reference)
//
#include <hip/hip_runtime.h>

#define N_TOTAL 4194304   // 2048*256*8
#define B_SIZE  2048
#define L_SIZE  256
#define I_DIM   8
#define H       32

// ---------------- Kernel A: global sum / sumsq over X ----------------
__global__ void reduce_sums(const float4* __restrict__ X4, double* __restrict__ ws) {
    int g = blockIdx.x * blockDim.x + threadIdx.x;
    int stride = gridDim.x * blockDim.x;
    float s1 = 0.f, s2 = 0.f;
    for (int i = g; i < N_TOTAL / 4; i += stride) {
        float4 v = X4[i];
        s1 += v.x + v.y + v.z + v.w;
        s2 += v.x * v.x + v.y * v.y + v.z * v.z + v.w * v.w;
    }
    for (int off = 32; off; off >>= 1) {
        s1 += __shfl_down(s1, off);
        s2 += __shfl_down(s2, off);
    }
    __shared__ float a1[4], a2[4];
    int lane = threadIdx.x & 63, wid = threadIdx.x >> 6;
    if (lane == 0) { a1[wid] = s1; a2[wid] = s2; }
    __syncthreads();
    if (threadIdx.x == 0) {
        atomicAdd(&ws[0], (double)(a1[0] + a1[1] + a1[2] + a1[3]));
        atomicAdd(&ws[1], (double)(a2[0] + a2[1] + a2[2] + a2[3]));
    }
}

// ---------------- Kernel B: fold all small weights into u,c,c2,M,m0,vW2,tW2 ----
// cst layout: [0..7]=u, [8]=c, [9]=c2(cls score), [10..25]=M[8][2] row-major,
//             [26..27]=m0, [28..29]=vcls@W2, [30..31]=(cls@W_t)@W2
__global__ void precompute(const double* __restrict__ sums,
                           const float* __restrict__ W1, const float* __restrict__ cls,
                           const float* __restrict__ Wq, const float* __restrict__ Wk,
                           const float* __restrict__ Wv, const float* __restrict__ Wt,
                           const float* __restrict__ W2, float* __restrict__ cst) {
    __shared__ float qv[H], kcls[H], vcls[H], tv[H], g[H], WV[I_DIM][H];
    __shared__ float uu[I_DIM], MM[I_DIM][2];
    int h = threadIdx.x;  // 0..31
    double sum = sums[0], sumsq = sums[1];
    double mu = sum / (double)N_TOTAL;
    double var = (sumsq - sum * sum / (double)N_TOTAL) / (double)(N_TOTAL - 1);
    float s = (float)(sqrt(var) + 1e-7);
    const float rs32 = 0.17677669529663687f;  // 1/sqrt(32)

    float q_ = 0.f, k_ = 0.f, v_ = 0.f, t_ = 0.f;
    for (int j = 0; j < H; j++) {
        float cj = cls[j];
        q_ += cj * Wq[j * H + h];
        k_ += cj * Wk[j * H + h];
        v_ += cj * Wv[j * H + h];
        t_ += cj * Wt[j * H + h];
    }
    qv[h] = q_; kcls[h] = k_; vcls[h] = v_; tv[h] = t_;
    __syncthreads();
    float g_ = 0.f;
    for (int j = 0; j < H; j++) g_ += Wk[h * H + j] * qv[j];   // g = W_k @ q
    g[h] = g_;
    for (int i = 0; i < I_DIM; i++) {                          // WV = W1 @ W_v, col h
        float a = 0.f;
        for (int j = 0; j < H; j++) a += W1[i * H + j] * Wv[j * H + h];
        WV[i][h] = a;
    }
    __syncthreads();
    if (h < I_DIM) {
        float a = 0.f;
        for (int j = 0; j < H; j++) a += W1[h * H + j] * g[j];
        uu[h] = a / s * rs32;
    }
    if (h < I_DIM * 2) {
        int i = h >> 1, o = h & 1;
        float a = 0.f;
        for (int j = 0; j < H; j++) a += WV[i][j] * W2[j * 2 + o];
        MM[i][o] = a / s;
    }
    __syncthreads();
    if (h == 0) {
        float csum = 0.f;
        for (int i = 0; i < I_DIM; i++) { cst[i] = uu[i]; csum += uu[i]; }
        cst[8] = (float)(-mu) * csum;
        float c2 = 0.f;
        for (int j = 0; j < H; j++) c2 += qv[j] * kcls[j];
        cst[9] = c2 * rs32;
        float m00 = 0.f, m01 = 0.f;
        for (int i = 0; i < I_DIM; i++) {
            cst[10 + i * 2] = MM[i][0]; cst[10 + i * 2 + 1] = MM[i][1];
            m00 += MM[i][0]; m01 += MM[i][1];
        }
        cst[26] = (float)(-mu) * m00;
        cst[27] = (float)(-mu) * m01;
        float vw0 = 0.f, vw1 = 0.f, tw0 = 0.f, tw1 = 0.f;
        for (int j = 0; j < H; j++) {
            vw0 += vcls[j] * W2[j * 2];     vw1 += vcls[j] * W2[j * 2 + 1];
            tw0 += tv[j]   * W2[j * 2];     tw1 += tv[j]   * W2[j * 2 + 1];
        }
        cst[28] = vw0; cst[29] = vw1; cst[30] = tw0; cst[31] = tw1;
    }
}

// ---------------- Kernel C: one block per batch row ----------------
__global__ __launch_bounds__(256) void attn_loss(const float* __restrict__ X,
                                                 const int* __restrict__ y,
                                                 const float* __restrict__ cst_g,
                                                 double* __restrict__ loss) {
    __shared__ float cst[32];
    __shared__ float wmax[4];
    __shared__ float wsum[4][9];
    int k = threadIdx.x;     // position 0..255
    int b = blockIdx.x;
    if (k < 32) cst[k] = cst_g[k];
    __syncthreads();

    const float4* Xb = (const float4*)(X + (size_t)b * (L_SIZE * I_DIM));
    float4 x0 = Xb[k * 2], x1 = Xb[k * 2 + 1];
    float x[8] = {x0.x, x0.y, x0.z, x0.w, x1.x, x1.y, x1.z, x1.w};

    float sc = cst[8];
    #pragma unroll
    for (int i = 0; i < 8; i++) sc += x[i] * cst[i];

    // block max (include cls score cst[9])
    float m = sc;
    for (int off = 32; off; off >>= 1) m = fmaxf(m, __shfl_down(m, off));
    int lane = k & 63, wid = k >> 6;
    if (lane == 0) wmax[wid] = m;
    __syncthreads();
    m = fmaxf(fmaxf(wmax[0], wmax[1]), fmaxf(wmax[2], wmax[3]));
    m = fmaxf(m, cst[9]);

    float e = expf(sc - m);
    float v[9];
    v[0] = e;
    #pragma unroll
    for (int i = 0; i < 8; i++) v[i + 1] = e * x[i];
    for (int off = 32; off; off >>= 1) {
        #pragma unroll
        for (int j = 0; j < 9; j++) v[j] += __shfl_down(v[j], off);
    }
    if (lane == 0) {
        #pragma unroll
        for (int j = 0; j < 9; j++) wsum[wid][j] = v[j];
    }
    __syncthreads();

    if (k == 0) {
        float se = wsum[0][0] + wsum[1][0] + wsum[2][0] + wsum[3][0];
        float ecls = expf(cst[9] - m);
        float denom = se + ecls;
        float inv = 1.f / denom;
        float S256 = ecls * inv;
        float z[2];
        #pragma unroll
        for (int o = 0; o < 2; o++) {
            float a = 0.f;
            #pragma unroll
            for (int i = 0; i < 8; i++) {
                float wi = (wsum[0][i + 1] + wsum[1][i + 1] + wsum[2][i + 1] + wsum[3][i + 1]) * inv;
                a += wi * cst[10 + i * 2 + o];
            }
            z[o] = a + (1.f - S256) * cst[26 + o] + S256 * cst[28 + o] + cst[30 + o];
        }
        float zm = fmaxf(z[0], z[1]);
        float lse = zm + logf(expf(z[0] - zm) + expf(z[1] - zm));
        int yb = y[b];
        float lb = lse - z[yb];
        atomicAdd(loss, (double)lb);
    }
}

// ---------------- Kernel D: finalize ----------------
__global__ void finalize(const double* __restrict__ loss, float* __restrict__ out) {
    out[0] = (float)(loss[0] / (double)B_SIZE);
}

extern "C" void kernel_launch(void* const* d_in, const int* in_sizes, int n_in,
                              void* d_out, int out_size, void* d_ws, size_t ws_size,
                              hipStream_t stream) {
    const float* X   = (const float*)d_in[0];
    const int*   y   = (const int*)d_in[1];
    const float* W1  = (const float*)d_in[2];
    const float* cls = (const float*)d_in[3];
    const float* Wq  = (const float*)d_in[4];
    const float* Wk  = (const float*)d_in[5];
    const float* Wv  = (const float*)d_in[6];
    const float* Wt  = (const float*)d_in[7];
    const float* W2  = (const float*)d_in[8];
    float* out = (float*)d_out;

    double* wsd = (double*)d_ws;           // [0]=sum, [1]=sumsq, [2]=loss
    float*  cst = (float*)d_ws + 8;        // 32 floats at byte offset 32

    hipMemsetAsync(d_ws, 0, 32, stream);
    hipLaunchKernelGGL(reduce_sums, dim3(1024), dim3(256), 0, stream, (const float4*)X, wsd);
    hipLaunchKernelGGL(precompute, dim3(1), dim3(32), 0, stream,
                       wsd, W1, cls, Wq, Wk, Wv, Wt, W2, cst);
    hipLaunchKernelGGL(attn_loss, dim3(B_SIZE), dim3(256), 0, stream, X, y, cst, wsd + 2);
    hipLaunchKernelGGL(finalize, dim3(1), dim3(1), 0, stream, wsd + 2, out);
}